// Round 4
// baseline (455.198 us; speedup 1.0000x reference)
//
#include <hip/hip_runtime.h>
#include <hip/hip_bf16.h>

// B=8, S=2048, DMODEL=1024, DK=128
typedef __bf16 bf16x8 __attribute__((ext_vector_type(8)));
typedef float  f32x4  __attribute__((ext_vector_type(4)));

// ---------------- workspace layout (bf16 elements) ----------------
// wpackF: [3][hi/lo][131072] fragment-ordered W        = 0 .. 786432
// q:      [16384][128] row-major                        at 786432
// kpack:  [256 tiles][1024 chunks][8] fragment-ordered  at 2883584
// vpack:  [256 tiles][1024 chunks][8] fragment-ordered  at 4980736
// fp32 K-split partials after 14155776 bytes
#define WS_Q  786432
#define WS_KP 2883584
#define WS_VP 4980736
#define WS_BF16_BYTES 14155776ull

// ---------------------------------------------------------------------------
// Kernel 1: Wq/Wk/Wv fp32 -> split bf16 (hi+lo) in MFMA B-fragment order.
// chunk c = ((kk*2+ks)*8+nt)*64 + lane ; elem j:
//   col = nt*16 + (lane&15), k = kk*64 + ks*32 + (lane>>4)*8 + j.
// Scale (1/sqrt(128))*log2(e) folded into Wq (softmax in log2 domain).
// ---------------------------------------------------------------------------
__global__ __launch_bounds__(256) void wconv_kernel(
    const float* __restrict__ wq, const float* __restrict__ wk,
    const float* __restrict__ wv, __bf16* __restrict__ wpack)
{
    int i = blockIdx.x * 256 + threadIdx.x;     // 0 .. 393215
    int p = i >> 17, o = i & 131071;
    int c = o >> 3, j = o & 7;
    int l15 = c & 15, g = (c >> 4) & 3, nt = (c >> 6) & 7, ks = (c >> 9) & 1, kk = c >> 10;
    int col = nt * 16 + l15;
    int k = kk * 64 + ks * 32 + g * 8 + j;
    const float* src = (p == 0) ? wq : ((p == 1) ? wk : wv);
    float f = src[col * 1024 + k];
    if (p == 0) f *= (0.08838834764831845f * 1.44269504088896340736f);
    __bf16 h = (__bf16)f;
    __bf16 l = (__bf16)(f - (float)h);
    wpack[p * 262144 + o]          = h;
    wpack[p * 262144 + 131072 + o] = l;
}

// ---------------------------------------------------------------------------
// Kernel 2: projection GEMM.  Block = 128 threads (2 waves), 64 rows x 128
// cols; each wave 32 rows (2 m-frags) -> every W frag feeds 2 MFMAs.
// W (hi+lo) staged in LDS per 32-k half, double-buffered, 1 barrier/half.
// x loaded global->regs with next-kk prefetch. grid (256,3) = 768 = 3/CU.
// ---------------------------------------------------------------------------
__global__ __launch_bounds__(128) void proj_kernel(
    const float* __restrict__ xq, const float* __restrict__ xk,
    const float* __restrict__ xv, const __bf16* __restrict__ wpack,
    __bf16* __restrict__ qws, __bf16* __restrict__ kpack, __bf16* __restrict__ vpack)
{
    const int p = blockIdx.y;
    const float* __restrict__ x = (p == 0) ? xq : ((p == 1) ? xk : xv);
    const __bf16* __restrict__ wf = wpack + p * 262144;   // hi plane; lo +131072

    const int mtile = blockIdx.x;               // [0,256)
    const int m0 = mtile << 6;                  // 64 rows/block
    const int t = threadIdx.x;
    const int w = t >> 6;                       // wave 0/1
    const int lane = t & 63;
    const int l15 = lane & 15, g = lane >> 4;

    // LDS: W double buffer 2 x 8192 bf16 (hi[0..4096) lo[4096..8192)) + olds
    __shared__ __align__(16) __bf16 wlds[2][8192];
    __shared__ __align__(16) __bf16 olds[9216];

    f32x4 acc[2][8];
#pragma unroll
    for (int mt = 0; mt < 2; ++mt)
#pragma unroll
        for (int nt = 0; nt < 8; ++nt) acc[mt][nt] = (f32x4){0.f, 0.f, 0.f, 0.f};

    // x base pointers: wave w covers rows m0 + w*32 + mt*16 + l15
    const float* xb[2];
    xb[0] = x + (size_t)(m0 + w * 32 + l15) * 1024 + g * 8;
    xb[1] = xb[0] + 16 * 1024;

    // x pipeline: per kk, per mt: 16 floats (ks in {0,1}, halves h in {0,1})
    f32x4 xc[2][4], xn[2][4];
#pragma unroll
    for (int mt = 0; mt < 2; ++mt)
#pragma unroll
        for (int i = 0; i < 4; ++i)
            xc[mt][i] = *(const f32x4*)(xb[mt] + (i >> 1) * 32 + (i & 1) * 4);

    // staging helper: wave w stages segs w*8 .. w*8+7 (w=0: hi, w=1: lo)
    auto stage = [&](int hs, int buf) {
#pragma unroll
        for (int s = 0; s < 8; ++s) {
            int seg = w * 8 + s;
            const __bf16* src = wf + ((seg < 8) ? ((size_t)hs * 4096 + seg * 512)
                                                : (131072ull + (size_t)hs * 4096 + (seg - 8) * 512))
                                + lane * 8;
            *(bf16x8*)(&wlds[buf][seg * 512 + lane * 8]) = *(const bf16x8*)src;
        }
    };

    stage(0, 0);
    __syncthreads();

    for (int hs = 0; hs < 32; ++hs) {           // half = 32 k
        const int buf = hs & 1 ^ 0;             // current buffer = hs parity
        const int kk = hs >> 1, ks = hs & 1;

        // stage next half into other buffer (overlaps compute)
        if (hs < 31) stage(hs + 1, buf ^ 1);

        // x prefetch for next kk at start of each kk
        if (ks == 0) {
            int nkk = (kk < 15) ? kk + 1 : 0;   // wrap: harmless re-read
#pragma unroll
            for (int mt = 0; mt < 2; ++mt)
#pragma unroll
                for (int i = 0; i < 4; ++i)
                    xn[mt][i] = *(const f32x4*)(xb[mt] + nkk * 64 + (i >> 1) * 32 + (i & 1) * 4);
        }

        // convert this half's x to bf16 A-frags
        bf16x8 ah[2];
#pragma unroll
        for (int mt = 0; mt < 2; ++mt)
#pragma unroll
            for (int e = 0; e < 8; ++e)
                ah[mt][e] = (__bf16)xc[mt][ks * 2 + (e >> 2)][e & 3];

        // 8 n-tiles x (hi,lo) x 2 m -> 32 MFMA
#pragma unroll
        for (int nt = 0; nt < 8; ++nt) {
            bf16x8 bh = *(const bf16x8*)(&wlds[buf][nt * 512 + lane * 8]);
            bf16x8 bl = *(const bf16x8*)(&wlds[buf][4096 + nt * 512 + lane * 8]);
#pragma unroll
            for (int mt = 0; mt < 2; ++mt) {
                acc[mt][nt] = __builtin_amdgcn_mfma_f32_16x16x32_bf16(ah[mt], bh, acc[mt][nt], 0, 0, 0);
                acc[mt][nt] = __builtin_amdgcn_mfma_f32_16x16x32_bf16(ah[mt], bl, acc[mt][nt], 0, 0, 0);
            }
        }

        if (ks == 1) {
#pragma unroll
            for (int mt = 0; mt < 2; ++mt)
#pragma unroll
                for (int i = 0; i < 4; ++i) xc[mt][i] = xn[mt][i];
        }
        __syncthreads();                        // staging done + buf free
    }

    // ---- epilogue: C frags -> LDS (q,k: [64][136]; v transposed: [128][72])
#pragma unroll
    for (int mt = 0; mt < 2; ++mt)
#pragma unroll
        for (int nt = 0; nt < 8; ++nt)
#pragma unroll
            for (int r = 0; r < 4; ++r) {
                int rowl = w * 32 + mt * 16 + g * 4 + r;
                int col = nt * 16 + l15;
                __bf16 v = (__bf16)acc[mt][nt][r];
                if (p < 2) olds[rowl * 136 + col] = v;
                else       olds[col * 72 + rowl] = v;
            }
    __syncthreads();

    if (p == 0) {
#pragma unroll
        for (int i = 0; i < 8; ++i) {
            int idx = i * 128 + t;
            int row = idx >> 4, ck = idx & 15;
            bf16x8 v = *(const bf16x8*)(olds + row * 136 + ck * 8);
            *(bf16x8*)(qws + (size_t)(m0 + row) * 128 + ck * 8) = v;
        }
    } else if (p == 1) {
        // kpack chunk idx = (ks*4+nt)*64+ln : elem j = K[nt*16+ll][ks*32+gg*8+j]
#pragma unroll
        for (int i = 0; i < 8; ++i) {
            int idx = i * 128 + t;
            int ks = idx >> 8, nt = (idx >> 6) & 3, ln = idx & 63;
            int gg = ln >> 4, ll = ln & 15;
            bf16x8 v = *(const bf16x8*)(olds + (nt * 16 + ll) * 136 + ks * 32 + gg * 8);
            *(bf16x8*)(kpack + ((size_t)mtile * 1024 + idx) * 8) = v;
        }
    } else {
        // vpack chunk idx = (ks2*8+nt2)*64+ln : elem j = V[ks2*32+gg*8+j][nt2*16+ll]
#pragma unroll
        for (int i = 0; i < 8; ++i) {
            int idx = i * 128 + t;
            int ks2 = idx >> 9, nt2 = (idx >> 6) & 7, ln = idx & 63;
            int gg = ln >> 4, ll = ln & 15;
            bf16x8 v = *(const bf16x8*)(olds + (nt2 * 16 + ll) * 72 + ks2 * 32 + gg * 8);
            *(bf16x8*)(vpack + ((size_t)mtile * 1024 + idx) * 8) = v;
        }
    }
}

// ---------------------------------------------------------------------------
// Kernel 3: flash attention, no barriers. BLOCK_M=64 (4 waves x 16 rows),
// BLOCK_N=64. K/V B-frags direct from fragment-packed global (per-XCD L2:
// bb = blockIdx&7). V frags preloaded before softmax; next-tile mask
// prefetched. Softmax in log2 domain (L2E folded into Wq).
// ---------------------------------------------------------------------------
__global__ __launch_bounds__(256) void flash_kernel(
    const __bf16* __restrict__ qws, const __bf16* __restrict__ kpack,
    const __bf16* __restrict__ vpack, const int* __restrict__ mask,
    float* __restrict__ out, float* __restrict__ part, float* __restrict__ mlbuf,
    int ktp)
{
    const int bb = blockIdx.x & 7;
    const int rest = blockIdx.x >> 3;
    const int mtile = rest & 31;
    const int jsplit = rest >> 5;
    const int sq0 = mtile << 6;
    const int t = threadIdx.x;
    const int wv_ = t >> 6;
    const int lane = t & 63;
    const int l15 = lane & 15, g = lane >> 4;

    __shared__ __align__(16) __bf16 psmem[4 * 1152];
    __bf16* plds = psmem + wv_ * 1152;

    bf16x8 qf[4];
    {
        const __bf16* qp = qws + ((size_t)(bb * 2048 + sq0 + wv_ * 16 + l15)) * 128 + g * 8;
#pragma unroll
        for (int ks = 0; ks < 4; ++ks) qf[ks] = *(const bf16x8*)(qp + ks * 32);
    }

    f32x4 o[8];
#pragma unroll
    for (int nt = 0; nt < 8; ++nt) o[nt] = (f32x4){0.f, 0.f, 0.f, 0.f};
    float m_run[4], l_run[4];
#pragma unroll
    for (int r = 0; r < 4; ++r) { m_run[r] = -__builtin_inff(); l_run[r] = 0.f; }

    const int* mbase = mask + ((size_t)(bb * 2048 + sq0 + wv_ * 16 + g * 4)) * 2048 + l15;
    const __bf16* kbase = kpack + ((size_t)(bb * 32) * 1024) * 8 + lane * 8;
    const __bf16* vbase = vpack + ((size_t)(bb * 32) * 1024) * 8 + lane * 8;

    const int kt_begin = jsplit * ktp, kt_end = kt_begin + ktp;

    // prologue: mask for first tile
    int mv[4][4];
#pragma unroll
    for (int nt = 0; nt < 4; ++nt)
#pragma unroll
        for (int r = 0; r < 4; ++r)
            mv[nt][r] = mbase[(size_t)r * 2048 + kt_begin * 64 + nt * 16];

    for (int kt = kt_begin; kt < kt_end; ++kt) {
        // K fragments: all 16 loads in flight, then QK MFMAs
        const __bf16* kb = kbase + kt * 8192;
        bf16x8 kfr[16];
#pragma unroll
        for (int i = 0; i < 16; ++i) kfr[i] = *(const bf16x8*)(kb + i * 512);

        f32x4 sf[4];
#pragma unroll
        for (int nt = 0; nt < 4; ++nt) sf[nt] = (f32x4){0.f, 0.f, 0.f, 0.f};
#pragma unroll
        for (int nt = 0; nt < 4; ++nt)
#pragma unroll
            for (int ks = 0; ks < 4; ++ks)
                sf[nt] = __builtin_amdgcn_mfma_f32_16x16x32_bf16(qf[ks], kfr[ks * 4 + nt], sf[nt], 0, 0, 0);

        // V fragments issued now; latency hides under softmax VALU
        const __bf16* vb = vbase + kt * 8192;
        bf16x8 vfr[16];
#pragma unroll
        for (int i = 0; i < 16; ++i) vfr[i] = *(const bf16x8*)(vb + i * 512);

        // next tile's mask
        int ktn = (kt + 1 < kt_end) ? kt + 1 : kt_begin;
        int mvn[4][4];
#pragma unroll
        for (int nt = 0; nt < 4; ++nt)
#pragma unroll
            for (int r = 0; r < 4; ++r)
                mvn[nt][r] = mbase[(size_t)r * 2048 + ktn * 64 + nt * 16];

        // online softmax (rows g*4+r; reduce across 16 l15 lanes)
        float mx[4], mnew[4], alpha[4], psum[4];
#pragma unroll
        for (int r = 0; r < 4; ++r)
            mx[r] = fmaxf(fmaxf(sf[0][r], sf[1][r]), fmaxf(sf[2][r], sf[3][r]));
#pragma unroll
        for (int off = 1; off < 16; off <<= 1)
#pragma unroll
            for (int r = 0; r < 4; ++r)
                mx[r] = fmaxf(mx[r], __shfl_xor(mx[r], off, 64));
#pragma unroll
        for (int r = 0; r < 4; ++r) {
            mnew[r] = fmaxf(m_run[r], mx[r]);
            alpha[r] = exp2f(m_run[r] - mnew[r]);
            psum[r] = 0.f;
        }
#pragma unroll
        for (int nt = 0; nt < 4; ++nt)
#pragma unroll
            for (int r = 0; r < 4; ++r) {
                float pv = exp2f(sf[nt][r] - mnew[r]);
                pv = mv[nt][r] ? pv : 0.f;          // mask after exp: exact
                psum[r] += pv;
                plds[(g * 4 + r) * 72 + nt * 16 + l15] = (__bf16)pv;
            }
#pragma unroll
        for (int off = 1; off < 16; off <<= 1)
#pragma unroll
            for (int r = 0; r < 4; ++r)
                psum[r] += __shfl_xor(psum[r], off, 64);
#pragma unroll
        for (int r = 0; r < 4; ++r) {
            l_run[r] = l_run[r] * alpha[r] + psum[r];
            m_run[r] = mnew[r];
        }
#pragma unroll
        for (int nt = 0; nt < 8; ++nt)
#pragma unroll
            for (int r = 0; r < 4; ++r) o[nt][r] *= alpha[r];

        // P: C-layout -> A-layout via wave-private LDS
        bf16x8 pa[2];
#pragma unroll
        for (int ks2 = 0; ks2 < 2; ++ks2)
            pa[ks2] = *(const bf16x8*)(plds + l15 * 72 + ks2 * 32 + g * 8);

        // O += P V
#pragma unroll
        for (int nt2 = 0; nt2 < 8; ++nt2)
#pragma unroll
            for (int ks2 = 0; ks2 < 2; ++ks2)
                o[nt2] = __builtin_amdgcn_mfma_f32_16x16x32_bf16(pa[ks2], vfr[ks2 * 8 + nt2], o[nt2], 0, 0, 0);

#pragma unroll
        for (int nt = 0; nt < 4; ++nt)
#pragma unroll
            for (int r = 0; r < 4; ++r) mv[nt][r] = mvn[nt][r];
    }

    if (part == nullptr) {
        float inv[4];
#pragma unroll
        for (int r = 0; r < 4; ++r) inv[r] = 1.0f / l_run[r];
#pragma unroll
        for (int nt2 = 0; nt2 < 8; ++nt2)
#pragma unroll
            for (int r = 0; r < 4; ++r)
                out[((size_t)(bb * 2048 + sq0 + wv_ * 16 + g * 4 + r)) * 128 + nt2 * 16 + l15] =
                    o[nt2][r] * inv[r];
    } else {
#pragma unroll
        for (int nt2 = 0; nt2 < 8; ++nt2)
#pragma unroll
            for (int r = 0; r < 4; ++r) {
                size_t rowg = (size_t)(bb * 2048 + sq0 + wv_ * 16 + g * 4 + r);
                part[((size_t)jsplit * 16384 + rowg) * 128 + nt2 * 16 + l15] = o[nt2][r];
            }
        if (l15 == 0) {
#pragma unroll
            for (int r = 0; r < 4; ++r) {
                size_t rowg = (size_t)(bb * 2048 + sq0 + wv_ * 16 + g * 4 + r);
                mlbuf[((size_t)jsplit * 16384 + rowg) * 2]     = m_run[r];
                mlbuf[((size_t)jsplit * 16384 + rowg) * 2 + 1] = l_run[r];
            }
        }
    }
}

// ---------------------------------------------------------------------------
// Kernel 4: merge K-split partials (log2-domain m).
// ---------------------------------------------------------------------------
__global__ __launch_bounds__(256) void merge_kernel(
    const float* __restrict__ part, const float* __restrict__ mlbuf,
    float* __restrict__ out, int J)
{
    int t = threadIdx.x;
    size_t row = (size_t)blockIdx.x * 8 + (t >> 5);
    int c = (t & 31) * 4;
    float mj[4];
    float m = -__builtin_inff();
    for (int j = 0; j < J; ++j) {
        mj[j] = mlbuf[((size_t)j * 16384 + row) * 2];
        m = fmaxf(m, mj[j]);
    }
    float l = 0.f;
    f32x4 acc = (f32x4){0.f, 0.f, 0.f, 0.f};
    for (int j = 0; j < J; ++j) {
        float wgt = exp2f(mj[j] - m);
        l += wgt * mlbuf[((size_t)j * 16384 + row) * 2 + 1];
        f32x4 v = *(const f32x4*)(part + ((size_t)j * 16384 + row) * 128 + c);
#pragma unroll
        for (int e = 0; e < 4; ++e) acc[e] += wgt * v[e];
    }
    float inv = 1.0f / l;
#pragma unroll
    for (int e = 0; e < 4; ++e) acc[e] *= inv;
    *(f32x4*)(out + row * 128 + c) = acc;
}

// ---------------------------------------------------------------------------
extern "C" void kernel_launch(void* const* d_in, const int* in_sizes, int n_in,
                              void* d_out, int out_size, void* d_ws, size_t ws_size,
                              hipStream_t stream)
{
    const float* query = (const float*)d_in[0];
    const float* key   = (const float*)d_in[1];
    const float* value = (const float*)d_in[2];
    const int*   mask  = (const int*)d_in[3];
    const float* Wq    = (const float*)d_in[4];
    const float* Wk    = (const float*)d_in[5];
    const float* Wv    = (const float*)d_in[6];
    float* out = (float*)d_out;

    __bf16* wpack = (__bf16*)d_ws;
    __bf16* qws = wpack + WS_Q;
    __bf16* kpack = wpack + WS_KP;
    __bf16* vpack = wpack + WS_VP;

    // K-split from workspace budget: per split 16384*128*4 + 16384*8 bytes
    const size_t per_split = 16384ull * 128 * 4 + 16384ull * 8;
    int J = 1;
    if (ws_size >= WS_BF16_BYTES + 4 * per_split)      J = 4;
    else if (ws_size >= WS_BF16_BYTES + 2 * per_split) J = 2;
    float* part = (J > 1) ? (float*)((char*)d_ws + WS_BF16_BYTES) : nullptr;
    float* mlbuf = (J > 1) ? (part + (size_t)J * 16384 * 128) : nullptr;

    wconv_kernel<<<1536, 256, 0, stream>>>(Wq, Wk, Wv, wpack);
    proj_kernel<<<dim3(256, 3), 128, 0, stream>>>(query, key, value, wpack, qws, kpack, vpack);
    flash_kernel<<<256 * J, 256, 0, stream>>>(qws, kpack, vpack, mask, out, part, mlbuf, 32 / J);
    if (J > 1) merge_kernel<<<2048, 256, 0, stream>>>(part, mlbuf, out, J);
}